// Round 3
// baseline (113.925 us; speedup 1.0000x reference)
//
#include <hip/hip_runtime.h>
#include <hip/hip_bf16.h>
#include <stdint.h>

// CausalSelfAttention: B=8, T=2048, C=128, H=4, D=32. fp32 in / fp32 out.
// All three stages MFMA (bf16 inputs, fp32 accum):
//   qkv_mfma: qkv = x @ w_qkv + b (Q pre-scaled log2e/sqrt(D); V -> [bh][d][t])
//   attn:     flash attention, no-max softmax, swapped QK^T (mfma(K,Q)),
//             cvt_pk_bf16 packed P -> ds_write_b64 into [q][k] LDS.
//             128-query blocks: 8 waves share one K/V staging + barrier.
//             512 blocks, CU-balanced qt map (stride-256 pairs sum to 34 iters).
//   out_mfma: out = y @ w_proj + b (fp32 out)
// ws: qb 4MB | kb 4MB | vtb 4MB | yb bf16 4MB = 16MB

#define T_SEQ 2048
#define C_EMBD 128
#define NH 4
#define HD 32
#define BATCH 8
#define BHT (BATCH * NH)

typedef float f4  __attribute__((ext_vector_type(4)));
typedef short bh8 __attribute__((ext_vector_type(8)));
typedef unsigned long long ull;

__device__ __forceinline__ unsigned short f2bf(float f) {
    union { float f; unsigned u; } v; v.f = f;
    return (unsigned short)((v.u + 0x7fffu + ((v.u >> 16) & 1u)) >> 16);
}
__device__ __forceinline__ ull pk4(float a, float b, float c, float d) {
    return (ull)f2bf(a) | ((ull)f2bf(b) << 16) | ((ull)f2bf(c) << 32) | ((ull)f2bf(d) << 48);
}
// v_cvt_pk_bf16_f32: lo16 = bf16(a), hi16 = bf16(b), RNE. No builtin on gfx950.
__device__ __forceinline__ unsigned cvt_pk_bf16(float a, float b) {
    unsigned r;
    asm("v_cvt_pk_bf16_f32 %0, %1, %2" : "=v"(r) : "v"(a), "v"(b));
    return r;
}

// ---------------------------------------------------------------------------
// Kernel 1: qkv = x @ w_qkv + b_qkv via MFMA. Grid (nt=3, mt=256).
// Block: 256 thr = 4 waves; 64 rows x 128 cols per block, K=128.
// A[m=lane&15][k=quad*8+j], B[n=lane&15][k=quad*8+j], C/D[row=quad*4+r][col].
// ---------------------------------------------------------------------------
__global__ __launch_bounds__(256) void qkv_mfma(const float* __restrict__ x,
                                                const float* __restrict__ w,
                                                const float* __restrict__ bias,
                                                unsigned short* __restrict__ qb,
                                                unsigned short* __restrict__ kb,
                                                unsigned short* __restrict__ vtb) {
    constexpr int XR = 136;   // xs row stride (elems): 272B, 16B-aligned
    constexpr int WR = 136;   // wt row stride
    constexpr int VR = 72;    // vt row stride
    __shared__ __align__(16) unsigned short xs[64 * XR];
    __shared__ __align__(16) unsigned short wt[128 * WR];
    __shared__ __align__(16) unsigned short vt[128 * VR];

    const int nt = blockIdx.x;        // 0=Q 1=K 2=V (column tile of 128)
    const int mt = blockIdx.y;        // row tile of 64
    const int t0g = mt * 64;          // global row
    const int b = t0g >> 11;          // batch
    const int t0 = t0g & 2047;        // seq pos within batch
    const int tid = threadIdx.x;
    const int wave = tid >> 6;
    const int lane = tid & 63;
    const int col = lane & 15;
    const int quad = lane >> 4;

    // stage x tile 64x128 fp32 -> bf16 LDS
    for (int i = 0; i < 8; ++i) {
        const int idx = tid + i * 256;           // over 2048 float4
        const int row = idx >> 5, c4 = idx & 31;
        const float4 xv = *(const float4*)(x + (size_t)(t0g + row) * C_EMBD + c4 * 4);
        *(ull*)(&xs[row * XR + c4 * 4]) = pk4(xv.x, xv.y, xv.z, xv.w);
    }
    // stage w slice [128k][128n] -> transposed bf16 LDS wt[n][k]
    for (int i = 0; i < 16; ++i) {
        const int idx = tid + i * 256;           // over 128n x 32 k-quads
        const int n = idx & 127, k4 = idx >> 7;
        const float w0 = w[(k4 * 4 + 0) * 384 + nt * 128 + n];
        const float w1 = w[(k4 * 4 + 1) * 384 + nt * 128 + n];
        const float w2 = w[(k4 * 4 + 2) * 384 + nt * 128 + n];
        const float w3 = w[(k4 * 4 + 3) * 384 + nt * 128 + n];
        *(ull*)(&wt[n * WR + k4 * 4]) = pk4(w0, w1, w2, w3);
    }
    __syncthreads();

    f4 acc[8];
#pragma unroll
    for (int nf = 0; nf < 8; ++nf) {
        const float bv = bias[nt * 128 + nf * 16 + col];
        acc[nf] = (f4){bv, bv, bv, bv};
    }
#pragma unroll
    for (int ch = 0; ch < 4; ++ch) {
        const bh8 af = *(const bh8*)(&xs[(wave * 16 + col) * XR + ch * 32 + quad * 8]);
#pragma unroll
        for (int nf = 0; nf < 8; ++nf) {
            const bh8 bf = *(const bh8*)(&wt[(nf * 16 + col) * WR + ch * 32 + quad * 8]);
            acc[nf] = __builtin_amdgcn_mfma_f32_16x16x32_bf16(af, bf, acc[nf], 0, 0, 0);
        }
    }

    const int mrow = wave * 16 + quad * 4;       // + r
    if (nt < 2) {
        unsigned short* outp = (nt == 0) ? qb : kb;
        const float sc = (nt == 0) ? 0.25503485952317864f : 1.0f;  // log2(e)/sqrt(32)
#pragma unroll
        for (int nf = 0; nf < 8; ++nf) {
            const int n = nf * 16 + col, h = n >> 5, d = n & 31;
            const size_t base = ((size_t)(b * NH + h) * T_SEQ + t0 + mrow) * HD + d;
#pragma unroll
            for (int r = 0; r < 4; ++r)
                outp[base + (size_t)r * HD] = f2bf(acc[nf][r] * sc);
        }
    } else {
        // V: C/D -> vt[n][m] LDS, then coalesced transposed writeout
#pragma unroll
        for (int nf = 0; nf < 8; ++nf) {
            const int n = nf * 16 + col;
#pragma unroll
            for (int r = 0; r < 4; ++r)
                vt[n * VR + mrow + r] = f2bf(acc[nf][r]);
        }
        __syncthreads();
        for (int i = 0; i < 16; ++i) {
            const int idx = tid + i * 256;       // over 128n x 32 uint-cols
            const int c = idx >> 5, dw = idx & 31;
            const int h2 = c >> 5, d2 = c & 31;
            const unsigned v0 = *(const unsigned*)(&vt[c * VR + dw * 2]);
            *(unsigned*)(vtb + ((size_t)(b * NH + h2) * HD + d2) * T_SEQ + t0 + dw * 2) = v0;
        }
    }
}

// ---------------------------------------------------------------------------
// Kernel 2: MFMA flash attention, no-max softmax, 128-query blocks.
// 8 waves (512 thr) share one K/V staging + one barrier per 64-key tile.
// Swapped QK^T: z = mfma(kfrag, qfrag) -> lane holds S[key=16f+4*quad+r][q=col];
// P packs with v_cvt_pk_bf16_f32 along keys, ds_write_b64 into [q][k] LDS.
// Grid 512: (bh, qt) with CU-balanced qt map: g<8 -> 15-g, else g-8, so the
// stride-256 pair per CU sums to 34 iterations regardless of g0.
// Waves fully above the causal diagonal skip compute (still hit barriers).
// ---------------------------------------------------------------------------
__global__ __launch_bounds__(512, 4) void attn(const unsigned short* __restrict__ qb,
                                               const unsigned short* __restrict__ kb,
                                               const unsigned short* __restrict__ vtb,
                                               unsigned short* __restrict__ y) {
    constexpr int KROW = 40;
    constexpr int VROW = 72;
    constexpr int PROW = 72;
    __shared__ __align__(16) unsigned short Ks[2][64 * KROW];
    __shared__ __align__(16) unsigned short Vt[2][32 * VROW];
    __shared__ __align__(16) unsigned short Pb[8][16 * PROW];

    const int bid = blockIdx.x;
    const int bh = bid & 31;
    const int g = bid >> 5;                       // 0..15
    const int qt = (g < 8) ? (15 - g) : (g - 8);  // CU-balanced map
    const int tid = threadIdx.x;
    const int wave = tid >> 6;                    // 0..7
    const int lane = tid & 63;
    const int col = lane & 15;
    const int quad = lane >> 4;

    const unsigned short* kbase = kb + (size_t)bh * T_SEQ * HD;
    const unsigned short* vbase = vtb + (size_t)bh * HD * T_SEQ;

    // staging roles: waves 0-3 stage K (64x32), waves 4-7 stage V (32x64)
    const bool stageK = (tid < 256);
    const int ks_t = tid >> 2, ks_q = tid & 3;          // K: t row 0..63, 16B col
    const int vs_d = (tid & 255) >> 3, vs_s = tid & 7;  // V: d row 0..31, 16B col

    const int q0 = qt * 128;
    const int ntiles = 2 * qt + 2;
    const int lim = 8 * qt + wave;    // max global key-16-block this wave needs

    // Per-wave 16 queries: q = q0 + wave*16 + col (B-frag n-index)
    const bh8 qfrag = *(const bh8*)(qb + ((size_t)bh * T_SEQ + q0 + wave * 16 + col) * HD + quad * 8);
    f4 yacc0 = {0.f, 0.f, 0.f, 0.f}, yacc1 = {0.f, 0.f, 0.f, 0.f};
    float rs = 0.f;   // running denom for query = col (own 16 keys/computed tile)

    uint4 reg = stageK
        ? *(const uint4*)(kbase + (size_t)ks_t * HD + ks_q * 8)
        : *(const uint4*)(vbase + (size_t)vs_d * T_SEQ + vs_s * 8);

    for (int kt = 0; kt < ntiles; ++kt) {
        const int buf = kt & 1;
        if (stageK) *(uint4*)(&Ks[buf][ks_t * KROW + ks_q * 8]) = reg;
        else        *(uint4*)(&Vt[buf][vs_d * VROW + vs_s * 8]) = reg;
        if (kt + 1 < ntiles) {
            reg = stageK
                ? *(const uint4*)(kbase + (size_t)((kt + 1) * 64 + ks_t) * HD + ks_q * 8)
                : *(const uint4*)(vbase + (size_t)vs_d * T_SEQ + (kt + 1) * 64 + vs_s * 8);
        }
        __syncthreads();

        const int rel = lim - 4 * kt;   // f < rel: full; f == rel: diag; f > rel: masked
        if (rel >= 0) {                 // wave-uniform: skip tiles fully above diagonal
            f4 z[4];
#pragma unroll
            for (int f = 0; f < 4; ++f) {
                if (f > rel) {
                    z[f] = (f4){-1e30f, -1e30f, -1e30f, -1e30f};
                } else {
                    // A = K (m = key), B = Q (n = query): swapped args.
                    const bh8 kfrag = *(const bh8*)(&Ks[buf][(f * 16 + col) * KROW + quad * 8]);
                    f4 zz = {0.f, 0.f, 0.f, 0.f};
                    zz = __builtin_amdgcn_mfma_f32_16x16x32_bf16(kfrag, qfrag, zz, 0, 0, 0);
                    if (f == rel) {
                        // mask key > query within 16x16: (quad*4+r) > col
#pragma unroll
                        for (int r = 0; r < 4; ++r)
                            if (quad * 4 + r > col) zz[r] = -1e30f;
                    }
                    z[f] = zz;
                }
            }
            // exp2 + packed P store: element (q=col, k=f*16+quad*4+r) -> Pb[q][k]
#pragma unroll
            for (int f = 0; f < 4; ++f) {
                const float p0 = __builtin_amdgcn_exp2f(z[f][0]);
                const float p1 = __builtin_amdgcn_exp2f(z[f][1]);
                const float p2 = __builtin_amdgcn_exp2f(z[f][2]);
                const float p3 = __builtin_amdgcn_exp2f(z[f][3]);
                rs += (p0 + p1) + (p2 + p3);
                const unsigned d01 = cvt_pk_bf16(p0, p1);
                const unsigned d23 = cvt_pk_bf16(p2, p3);
                *(ull*)(&Pb[wave][col * PROW + f * 16 + quad * 4]) = (ull)d01 | ((ull)d23 << 32);
            }
#pragma unroll
            for (int kk = 0; kk < 2; ++kk) {
                const bh8 pf = *(const bh8*)(&Pb[wave][col * PROW + kk * 32 + quad * 8]);
                const bh8 v0 = *(const bh8*)(&Vt[buf][col * VROW + kk * 32 + quad * 8]);
                yacc0 = __builtin_amdgcn_mfma_f32_16x16x32_bf16(pf, v0, yacc0, 0, 0, 0);
                const bh8 v1 = *(const bh8*)(&Vt[buf][(16 + col) * VROW + kk * 32 + quad * 8]);
                yacc1 = __builtin_amdgcn_mfma_f32_16x16x32_bf16(pf, v1, yacc1, 0, 0, 0);
            }
        }
    }

    // denom: rs holds sum over this lane's keys for query=col; keys spread
    // across quads -> reduce across quads only.
    rs += __shfl_xor(rs, 16);
    rs += __shfl_xor(rs, 32);
    const float inv = 1.0f / rs;      // inverse denom for query = col

    const int bb = bh >> 2, hh = bh & 3;
    unsigned short* yp = y + ((size_t)bb * T_SEQ + q0 + wave * 16) * C_EMBD + hh * HD;
#pragma unroll
    for (int r = 0; r < 4; ++r) {
        // yacc row = query quad*4+r; fetch inv from lane with col == quad*4+r (same quad)
        const float invr = __shfl(inv, (lane & 48) | (quad * 4 + r));
        yp[(quad * 4 + r) * C_EMBD + col] = f2bf(yacc0[r] * invr);
        yp[(quad * 4 + r) * C_EMBD + 16 + col] = f2bf(yacc1[r] * invr);
    }
}

// ---------------------------------------------------------------------------
// Kernel 3: out = y @ w_proj + b_proj via MFMA. Grid 256 (64 rows each).
// ---------------------------------------------------------------------------
__global__ __launch_bounds__(256) void out_mfma(const unsigned short* __restrict__ y,
                                                const float* __restrict__ w,
                                                const float* __restrict__ bias,
                                                float* __restrict__ out) {
    constexpr int YR = 136;
    constexpr int WR = 136;
    __shared__ __align__(16) unsigned short ys[64 * YR];
    __shared__ __align__(16) unsigned short wt[128 * WR];

    const int mt = blockIdx.x;
    const int row0 = mt * 64;
    const int tid = threadIdx.x;
    const int wave = tid >> 6;
    const int lane = tid & 63;
    const int col = lane & 15;
    const int quad = lane >> 4;

    // stage y tile 64x128 bf16 (direct copy)
    for (int i = 0; i < 4; ++i) {
        const int idx = tid + i * 256;           // over 1024 uint4
        const int row = idx >> 4, q8 = idx & 15;
        const uint4 v = *(const uint4*)(y + (size_t)(row0 + row) * C_EMBD + q8 * 8);
        *(uint4*)(&ys[row * YR + q8 * 8]) = v;
    }
    // stage w_proj [128k][128n] -> transposed bf16 wt[n][k]
    for (int i = 0; i < 16; ++i) {
        const int idx = tid + i * 256;
        const int n = idx & 127, k4 = idx >> 7;
        const float w0 = w[(k4 * 4 + 0) * C_EMBD + n];
        const float w1 = w[(k4 * 4 + 1) * C_EMBD + n];
        const float w2 = w[(k4 * 4 + 2) * C_EMBD + n];
        const float w3 = w[(k4 * 4 + 3) * C_EMBD + n];
        *(ull*)(&wt[n * WR + k4 * 4]) = pk4(w0, w1, w2, w3);
    }
    __syncthreads();

    f4 acc[8];
#pragma unroll
    for (int nf = 0; nf < 8; ++nf) {
        const float bv = bias[nf * 16 + col];
        acc[nf] = (f4){bv, bv, bv, bv};
    }
#pragma unroll
    for (int ch = 0; ch < 4; ++ch) {
        const bh8 af = *(const bh8*)(&ys[(wave * 16 + col) * YR + ch * 32 + quad * 8]);
#pragma unroll
        for (int nf = 0; nf < 8; ++nf) {
            const bh8 bf = *(const bh8*)(&wt[(nf * 16 + col) * WR + ch * 32 + quad * 8]);
            acc[nf] = __builtin_amdgcn_mfma_f32_16x16x32_bf16(af, bf, acc[nf], 0, 0, 0);
        }
    }

    const int mrow = wave * 16 + quad * 4;
#pragma unroll
    for (int nf = 0; nf < 8; ++nf)
#pragma unroll
        for (int r = 0; r < 4; ++r)
            out[(size_t)(row0 + mrow + r) * C_EMBD + nf * 16 + col] = acc[nf][r];
}

extern "C" void kernel_launch(void* const* d_in, const int* in_sizes, int n_in,
                              void* d_out, int out_size, void* d_ws, size_t ws_size,
                              hipStream_t stream) {
    const float* x      = (const float*)d_in[0];
    const float* w_qkv  = (const float*)d_in[1];
    const float* b_qkv  = (const float*)d_in[2];
    const float* w_proj = (const float*)d_in[3];
    const float* b_proj = (const float*)d_in[4];
    float* out = (float*)d_out;

    unsigned short* qb  = (unsigned short*)d_ws;                   // 4 MB
    unsigned short* kb  = qb + (size_t)BHT * T_SEQ * HD;           // 4 MB
    unsigned short* vtb = kb + (size_t)BHT * T_SEQ * HD;           // 4 MB
    unsigned short* yb  = vtb + (size_t)BHT * T_SEQ * HD;          // 4 MB (bf16 y)

    qkv_mfma<<<dim3(3, 256), 256, 0, stream>>>(x, w_qkv, b_qkv, qb, kb, vtb);
    attn<<<512, 512, 0, stream>>>(qb, kb, vtb, yb);
    out_mfma<<<256, 256, 0, stream>>>(yb, w_proj, b_proj, out);
}

// Round 4
// 104.771 us; speedup vs baseline: 1.0874x; 1.0874x over previous
//
#include <hip/hip_runtime.h>
#include <hip/hip_bf16.h>
#include <stdint.h>

// CausalSelfAttention: B=8, T=2048, C=128, H=4, D=32. fp32 in / fp32 out.
// All three stages MFMA (bf16 inputs, fp32 accum):
//   qkv_mfma: qkv = x @ w_qkv + b (Q pre-scaled log2e/sqrt(D); V -> [bh][d][t])
//   attn:     flash attention, no-max softmax, swapped QK^T (mfma(K,Q)) so
//             accumulator regs are key-consecutive -> cvt_pk_bf16 packed P,
//             ds_write_b64 into [q][k] LDS. 1024 single-q-tile blocks of
//             4 waves; CU-balanced qt map: co-resident blocks (bid mod 256)
//             get qt in {31-g, 16+g, 15-g, g} -> 66 iters per CU for all g.
//   out_mfma: out = y @ w_proj + b (fp32 out)
// ws: qb 4MB | kb 4MB | vtb 4MB | yb bf16 4MB = 16MB

#define T_SEQ 2048
#define C_EMBD 128
#define NH 4
#define HD 32
#define BATCH 8
#define BHT (BATCH * NH)

typedef float f4  __attribute__((ext_vector_type(4)));
typedef short bh8 __attribute__((ext_vector_type(8)));
typedef unsigned long long ull;

__device__ __forceinline__ unsigned short f2bf(float f) {
    union { float f; unsigned u; } v; v.f = f;
    return (unsigned short)((v.u + 0x7fffu + ((v.u >> 16) & 1u)) >> 16);
}
__device__ __forceinline__ ull pk4(float a, float b, float c, float d) {
    return (ull)f2bf(a) | ((ull)f2bf(b) << 16) | ((ull)f2bf(c) << 32) | ((ull)f2bf(d) << 48);
}
// v_cvt_pk_bf16_f32: lo16 = bf16(a), hi16 = bf16(b), RNE. No builtin on gfx950.
__device__ __forceinline__ unsigned cvt_pk_bf16(float a, float b) {
    unsigned r;
    asm("v_cvt_pk_bf16_f32 %0, %1, %2" : "=v"(r) : "v"(a), "v"(b));
    return r;
}

// ---------------------------------------------------------------------------
// Kernel 1: qkv = x @ w_qkv + b_qkv via MFMA. Grid (nt=3, mt=256).
// Block: 256 thr = 4 waves; 64 rows x 128 cols per block, K=128.
// A[m=lane&15][k=quad*8+j], B[n=lane&15][k=quad*8+j], C/D[row=quad*4+r][col].
// ---------------------------------------------------------------------------
__global__ __launch_bounds__(256) void qkv_mfma(const float* __restrict__ x,
                                                const float* __restrict__ w,
                                                const float* __restrict__ bias,
                                                unsigned short* __restrict__ qb,
                                                unsigned short* __restrict__ kb,
                                                unsigned short* __restrict__ vtb) {
    constexpr int XR = 136;   // xs row stride (elems): 272B, 16B-aligned
    constexpr int WR = 136;   // wt row stride
    constexpr int VR = 72;    // vt row stride
    __shared__ __align__(16) unsigned short xs[64 * XR];
    __shared__ __align__(16) unsigned short wt[128 * WR];
    __shared__ __align__(16) unsigned short vt[128 * VR];

    const int nt = blockIdx.x;        // 0=Q 1=K 2=V (column tile of 128)
    const int mt = blockIdx.y;        // row tile of 64
    const int t0g = mt * 64;          // global row
    const int b = t0g >> 11;          // batch
    const int t0 = t0g & 2047;        // seq pos within batch
    const int tid = threadIdx.x;
    const int wave = tid >> 6;
    const int lane = tid & 63;
    const int col = lane & 15;
    const int quad = lane >> 4;

    // stage x tile 64x128 fp32 -> bf16 LDS
    for (int i = 0; i < 8; ++i) {
        const int idx = tid + i * 256;           // over 2048 float4
        const int row = idx >> 5, c4 = idx & 31;
        const float4 xv = *(const float4*)(x + (size_t)(t0g + row) * C_EMBD + c4 * 4);
        *(ull*)(&xs[row * XR + c4 * 4]) = pk4(xv.x, xv.y, xv.z, xv.w);
    }
    // stage w slice [128k][128n] -> transposed bf16 LDS wt[n][k]
    for (int i = 0; i < 16; ++i) {
        const int idx = tid + i * 256;           // over 128n x 32 k-quads
        const int n = idx & 127, k4 = idx >> 7;
        const float w0 = w[(k4 * 4 + 0) * 384 + nt * 128 + n];
        const float w1 = w[(k4 * 4 + 1) * 384 + nt * 128 + n];
        const float w2 = w[(k4 * 4 + 2) * 384 + nt * 128 + n];
        const float w3 = w[(k4 * 4 + 3) * 384 + nt * 128 + n];
        *(ull*)(&wt[n * WR + k4 * 4]) = pk4(w0, w1, w2, w3);
    }
    __syncthreads();

    f4 acc[8];
#pragma unroll
    for (int nf = 0; nf < 8; ++nf) {
        const float bv = bias[nt * 128 + nf * 16 + col];
        acc[nf] = (f4){bv, bv, bv, bv};
    }
#pragma unroll
    for (int ch = 0; ch < 4; ++ch) {
        const bh8 af = *(const bh8*)(&xs[(wave * 16 + col) * XR + ch * 32 + quad * 8]);
#pragma unroll
        for (int nf = 0; nf < 8; ++nf) {
            const bh8 bf = *(const bh8*)(&wt[(nf * 16 + col) * WR + ch * 32 + quad * 8]);
            acc[nf] = __builtin_amdgcn_mfma_f32_16x16x32_bf16(af, bf, acc[nf], 0, 0, 0);
        }
    }

    const int mrow = wave * 16 + quad * 4;       // + r
    if (nt < 2) {
        unsigned short* outp = (nt == 0) ? qb : kb;
        const float sc = (nt == 0) ? 0.25503485952317864f : 1.0f;  // log2(e)/sqrt(32)
#pragma unroll
        for (int nf = 0; nf < 8; ++nf) {
            const int n = nf * 16 + col, h = n >> 5, d = n & 31;
            const size_t base = ((size_t)(b * NH + h) * T_SEQ + t0 + mrow) * HD + d;
#pragma unroll
            for (int r = 0; r < 4; ++r)
                outp[base + (size_t)r * HD] = f2bf(acc[nf][r] * sc);
        }
    } else {
        // V: C/D -> vt[n][m] LDS, then coalesced transposed writeout
#pragma unroll
        for (int nf = 0; nf < 8; ++nf) {
            const int n = nf * 16 + col;
#pragma unroll
            for (int r = 0; r < 4; ++r)
                vt[n * VR + mrow + r] = f2bf(acc[nf][r]);
        }
        __syncthreads();
        for (int i = 0; i < 16; ++i) {
            const int idx = tid + i * 256;       // over 128n x 32 uint-cols
            const int c = idx >> 5, dw = idx & 31;
            const int h2 = c >> 5, d2 = c & 31;
            const unsigned v0 = *(const unsigned*)(&vt[c * VR + dw * 2]);
            *(unsigned*)(vtb + ((size_t)(b * NH + h2) * HD + d2) * T_SEQ + t0 + dw * 2) = v0;
        }
    }
}

// ---------------------------------------------------------------------------
// Kernel 2: MFMA flash attention, no-max softmax, double-buffered staging.
// Swapped QK^T: z = mfma(kfrag, qfrag) -> lane holds S[key=16f+4*quad+r][q=col],
// so P packs with v_cvt_pk_bf16_f32 along keys and stores as b64 into [q][k].
// Grid 1024: one q-tile (64 queries) per block, 4 waves.
// CU-balanced qt map: co-resident blocks (same bid&255, c=bid>>8) get
// qt = {31-g, 16+g, 15-g, g}[c] -> sum(qt+1) = 66 for every CU.
// ---------------------------------------------------------------------------
__global__ __launch_bounds__(256, 4) void attn(const unsigned short* __restrict__ qb,
                                               const unsigned short* __restrict__ kb,
                                               const unsigned short* __restrict__ vtb,
                                               unsigned short* __restrict__ y) {
    constexpr int KROW = 40;
    constexpr int VROW = 72;
    constexpr int PROW = 72;
    __shared__ __align__(16) unsigned short Ks[2][64 * KROW];
    __shared__ __align__(16) unsigned short Vt[2][32 * VROW];
    __shared__ __align__(16) unsigned short Pb[4][16 * PROW];

    const int bid = blockIdx.x;
    const int bh = bid & 31;
    const int g = (bid >> 5) & 7;
    const int c = bid >> 8;           // 0..3: which co-residency round
    const int qt = (c == 0) ? (31 - g) : (c == 1) ? (16 + g) : (c == 2) ? (15 - g) : g;
    const int tid = threadIdx.x;
    const int wave = tid >> 6;
    const int lane = tid & 63;
    const int col = lane & 15;
    const int quad = lane >> 4;

    const unsigned short* kbase = kb + (size_t)bh * T_SEQ * HD;
    const unsigned short* vbase = vtb + (size_t)bh * HD * T_SEQ;
    const int ks_t = tid >> 2, ks_q = tid & 3;
    const int vs_d = tid >> 3, vs_s = tid & 7;

    const int q0 = qt * 64;
    const int ntiles = qt + 1;

    // Per-wave 16 queries: q = q0 + wave*16 + col (B-frag n-index)
    const bh8 qfrag = *(const bh8*)(qb + ((size_t)bh * T_SEQ + q0 + wave * 16 + col) * HD + quad * 8);
    f4 yacc0 = {0.f, 0.f, 0.f, 0.f}, yacc1 = {0.f, 0.f, 0.f, 0.f};
    float rs = 0.f;   // running denom for query = col (own 16 keys/iter)

    uint4 kreg = *(const uint4*)(kbase + (size_t)ks_t * HD + ks_q * 8);
    uint4 vreg = *(const uint4*)(vbase + (size_t)vs_d * T_SEQ + vs_s * 8);

    for (int kt = 0; kt < ntiles; ++kt) {
        const int buf = kt & 1;
        *(uint4*)(&Ks[buf][ks_t * KROW + ks_q * 8]) = kreg;
        *(uint4*)(&Vt[buf][vs_d * VROW + vs_s * 8]) = vreg;
        if (kt + 1 < ntiles) {
            kreg = *(const uint4*)(kbase + (size_t)((kt + 1) * 64 + ks_t) * HD + ks_q * 8);
            vreg = *(const uint4*)(vbase + (size_t)vs_d * T_SEQ + (kt + 1) * 64 + vs_s * 8);
        }
        __syncthreads();

        const bool diag = (kt == qt);
        f4 z[4];
#pragma unroll
        for (int f = 0; f < 4; ++f) {
            if (diag && f > wave) {
                z[f] = (f4){-1e30f, -1e30f, -1e30f, -1e30f};
            } else {
                // A = K (m = key), B = Q (n = query): same fragment loads, swapped args.
                const bh8 kfrag = *(const bh8*)(&Ks[buf][(f * 16 + col) * KROW + quad * 8]);
                f4 zz = {0.f, 0.f, 0.f, 0.f};
                zz = __builtin_amdgcn_mfma_f32_16x16x32_bf16(kfrag, qfrag, zz, 0, 0, 0);
                if (diag && f == wave) {
                    // mask key > query: (f*16 + quad*4 + r) > (wave*16 + col)
#pragma unroll
                    for (int r = 0; r < 4; ++r)
                        if (quad * 4 + r > col) zz[r] = -1e30f;
                }
                z[f] = zz;
            }
        }
        // exp2 + packed P store: element (q=col, k=f*16+quad*4+r) -> Pb[q][k]
#pragma unroll
        for (int f = 0; f < 4; ++f) {
            const float p0 = __builtin_amdgcn_exp2f(z[f][0]);
            const float p1 = __builtin_amdgcn_exp2f(z[f][1]);
            const float p2 = __builtin_amdgcn_exp2f(z[f][2]);
            const float p3 = __builtin_amdgcn_exp2f(z[f][3]);
            rs += (p0 + p1) + (p2 + p3);
            const unsigned d01 = cvt_pk_bf16(p0, p1);
            const unsigned d23 = cvt_pk_bf16(p2, p3);
            // col*PROW*2 bytes = col*144: 16B-aligned; + (f*16+quad*4)*2: 8B-aligned
            *(ull*)(&Pb[wave][col * PROW + f * 16 + quad * 4]) = (ull)d01 | ((ull)d23 << 32);
        }
#pragma unroll
        for (int kk = 0; kk < 2; ++kk) {
            const bh8 pf = *(const bh8*)(&Pb[wave][col * PROW + kk * 32 + quad * 8]);
            const bh8 v0 = *(const bh8*)(&Vt[buf][col * VROW + kk * 32 + quad * 8]);
            yacc0 = __builtin_amdgcn_mfma_f32_16x16x32_bf16(pf, v0, yacc0, 0, 0, 0);
            const bh8 v1 = *(const bh8*)(&Vt[buf][(16 + col) * VROW + kk * 32 + quad * 8]);
            yacc1 = __builtin_amdgcn_mfma_f32_16x16x32_bf16(pf, v1, yacc1, 0, 0, 0);
        }
    }

    // denom: rs holds sum over this lane's 16 keys/iter for query=col;
    // keys are spread across quads -> reduce across quads only.
    rs += __shfl_xor(rs, 16);
    rs += __shfl_xor(rs, 32);
    const float inv = 1.0f / rs;      // inverse denom for query = col

    const int bb = bh >> 2, hh = bh & 3;
    unsigned short* yp = y + ((size_t)bb * T_SEQ + q0 + wave * 16) * C_EMBD + hh * HD;
#pragma unroll
    for (int r = 0; r < 4; ++r) {
        // yacc row = query quad*4+r; fetch inv from lane with col == quad*4+r (same quad)
        const float invr = __shfl(inv, (lane & 48) | (quad * 4 + r));
        yp[(quad * 4 + r) * C_EMBD + col] = f2bf(yacc0[r] * invr);
        yp[(quad * 4 + r) * C_EMBD + 16 + col] = f2bf(yacc1[r] * invr);
    }
}

// ---------------------------------------------------------------------------
// Kernel 3: out = y @ w_proj + b_proj via MFMA. Grid 256 (64 rows each).
// ---------------------------------------------------------------------------
__global__ __launch_bounds__(256) void out_mfma(const unsigned short* __restrict__ y,
                                                const float* __restrict__ w,
                                                const float* __restrict__ bias,
                                                float* __restrict__ out) {
    constexpr int YR = 136;
    constexpr int WR = 136;
    __shared__ __align__(16) unsigned short ys[64 * YR];
    __shared__ __align__(16) unsigned short wt[128 * WR];

    const int mt = blockIdx.x;
    const int row0 = mt * 64;
    const int tid = threadIdx.x;
    const int wave = tid >> 6;
    const int lane = tid & 63;
    const int col = lane & 15;
    const int quad = lane >> 4;

    // stage y tile 64x128 bf16 (direct copy)
    for (int i = 0; i < 4; ++i) {
        const int idx = tid + i * 256;           // over 1024 uint4
        const int row = idx >> 4, q8 = idx & 15;
        const uint4 v = *(const uint4*)(y + (size_t)(row0 + row) * C_EMBD + q8 * 8);
        *(uint4*)(&ys[row * YR + q8 * 8]) = v;
    }
    // stage w_proj [128k][128n] -> transposed bf16 wt[n][k]
    for (int i = 0; i < 16; ++i) {
        const int idx = tid + i * 256;
        const int n = idx & 127, k4 = idx >> 7;
        const float w0 = w[(k4 * 4 + 0) * C_EMBD + n];
        const float w1 = w[(k4 * 4 + 1) * C_EMBD + n];
        const float w2 = w[(k4 * 4 + 2) * C_EMBD + n];
        const float w3 = w[(k4 * 4 + 3) * C_EMBD + n];
        *(ull*)(&wt[n * WR + k4 * 4]) = pk4(w0, w1, w2, w3);
    }
    __syncthreads();

    f4 acc[8];
#pragma unroll
    for (int nf = 0; nf < 8; ++nf) {
        const float bv = bias[nf * 16 + col];
        acc[nf] = (f4){bv, bv, bv, bv};
    }
#pragma unroll
    for (int ch = 0; ch < 4; ++ch) {
        const bh8 af = *(const bh8*)(&ys[(wave * 16 + col) * YR + ch * 32 + quad * 8]);
#pragma unroll
        for (int nf = 0; nf < 8; ++nf) {
            const bh8 bf = *(const bh8*)(&wt[(nf * 16 + col) * WR + ch * 32 + quad * 8]);
            acc[nf] = __builtin_amdgcn_mfma_f32_16x16x32_bf16(af, bf, acc[nf], 0, 0, 0);
        }
    }

    const int mrow = wave * 16 + quad * 4;
#pragma unroll
    for (int nf = 0; nf < 8; ++nf)
#pragma unroll
        for (int r = 0; r < 4; ++r)
            out[(size_t)(row0 + mrow + r) * C_EMBD + nf * 16 + col] = acc[nf][r];
}

extern "C" void kernel_launch(void* const* d_in, const int* in_sizes, int n_in,
                              void* d_out, int out_size, void* d_ws, size_t ws_size,
                              hipStream_t stream) {
    const float* x      = (const float*)d_in[0];
    const float* w_qkv  = (const float*)d_in[1];
    const float* b_qkv  = (const float*)d_in[2];
    const float* w_proj = (const float*)d_in[3];
    const float* b_proj = (const float*)d_in[4];
    float* out = (float*)d_out;

    unsigned short* qb  = (unsigned short*)d_ws;                   // 4 MB
    unsigned short* kb  = qb + (size_t)BHT * T_SEQ * HD;           // 4 MB
    unsigned short* vtb = kb + (size_t)BHT * T_SEQ * HD;           // 4 MB
    unsigned short* yb  = vtb + (size_t)BHT * T_SEQ * HD;          // 4 MB (bf16 y)

    qkv_mfma<<<dim3(3, 256), 256, 0, stream>>>(x, w_qkv, b_qkv, qb, kb, vtb);
    attn<<<1024, 256, 0, stream>>>(qb, kb, vtb, yb);
    out_mfma<<<256, 256, 0, stream>>>(yb, w_proj, b_proj, out);
}

// Round 5
// 103.272 us; speedup vs baseline: 1.1032x; 1.0145x over previous
//
#include <hip/hip_runtime.h>
#include <hip/hip_bf16.h>
#include <stdint.h>

// CausalSelfAttention: B=8, T=2048, C=128, H=4, D=32. fp32 in / fp32 out.
// All three stages MFMA (bf16 inputs, fp32 accum):
//   qkv_mfma: qkv = x @ w_qkv + b. Q/K use SWAPPED mfma (rows = w-cols) so the
//             4 acc regs are consecutive d -> cvt_pk packed b64 stores (8/thread).
//             V keeps old orientation -> vt LDS transpose -> [bh][d][t].
//   attn:     flash attention, no-max softmax, swapped QK^T (mfma(K,Q)),
//             cvt_pk packed P -> ds_write_b64 [q][k]. 1024 blocks, CU-balanced
//             qt map {31-g, 16+g, 15-g, g} -> 66 iters/CU.
//   out_mfma: out = y @ w_proj + b, SWAPPED mfma -> float4 stores (8/thread).
// ws: qb 4MB | kb 4MB | vtb 4MB | yb bf16 4MB = 16MB

#define T_SEQ 2048
#define C_EMBD 128
#define NH 4
#define HD 32
#define BATCH 8
#define BHT (BATCH * NH)

typedef float f4  __attribute__((ext_vector_type(4)));
typedef short bh8 __attribute__((ext_vector_type(8)));
typedef unsigned long long ull;

__device__ __forceinline__ unsigned short f2bf(float f) {
    union { float f; unsigned u; } v; v.f = f;
    return (unsigned short)((v.u + 0x7fffu + ((v.u >> 16) & 1u)) >> 16);
}
// v_cvt_pk_bf16_f32: lo16 = bf16(a), hi16 = bf16(b), RNE (== f2bf). No builtin.
__device__ __forceinline__ unsigned cvt_pk_bf16(float a, float b) {
    unsigned r;
    asm("v_cvt_pk_bf16_f32 %0, %1, %2" : "=v"(r) : "v"(a), "v"(b));
    return r;
}
__device__ __forceinline__ ull pk4(float a, float b, float c, float d) {
    return (ull)cvt_pk_bf16(a, b) | ((ull)cvt_pk_bf16(c, d) << 32);
}

// ---------------------------------------------------------------------------
// Kernel 1: qkv = x @ w_qkv + b_qkv via MFMA. Grid (nt=3, mt=256).
// Block: 256 thr = 4 waves; 64 rows x 128 cols per block, K=128.
// A[m=lane&15][k=quad*8+j], B[n=lane&15][k=quad*8+j], C/D[row=quad*4+r][col].
// Q/K: mfma(wf, xf) -> C rows = w-cols: regs are 4 consecutive d -> b64 stores.
// V:   mfma(xf, wf) -> C rows = t: vt LDS transpose -> coalesced [d][t] out.
// ---------------------------------------------------------------------------
__global__ __launch_bounds__(256) void qkv_mfma(const float* __restrict__ x,
                                                const float* __restrict__ w,
                                                const float* __restrict__ bias,
                                                unsigned short* __restrict__ qb,
                                                unsigned short* __restrict__ kb,
                                                unsigned short* __restrict__ vtb) {
    constexpr int XR = 136;   // xs row stride (elems): 272B, 16B-aligned
    constexpr int WR = 136;   // wt row stride
    constexpr int VR = 72;    // vt row stride
    __shared__ __align__(16) unsigned short xs[64 * XR];
    __shared__ __align__(16) unsigned short wt[128 * WR];
    __shared__ __align__(16) unsigned short vt[128 * VR];

    const int nt = blockIdx.x;        // 0=Q 1=K 2=V (column tile of 128)
    const int mt = blockIdx.y;        // row tile of 64
    const int t0g = mt * 64;          // global row
    const int b = t0g >> 11;          // batch
    const int t0 = t0g & 2047;        // seq pos within batch
    const int tid = threadIdx.x;
    const int wave = tid >> 6;
    const int lane = tid & 63;
    const int col = lane & 15;
    const int quad = lane >> 4;

    // stage x tile 64x128 fp32 -> bf16 LDS
    for (int i = 0; i < 8; ++i) {
        const int idx = tid + i * 256;           // over 2048 float4
        const int row = idx >> 5, c4 = idx & 31;
        const float4 xv = *(const float4*)(x + (size_t)(t0g + row) * C_EMBD + c4 * 4);
        *(ull*)(&xs[row * XR + c4 * 4]) = pk4(xv.x, xv.y, xv.z, xv.w);
    }
    // stage w slice [128k][128n] -> transposed bf16 LDS wt[n][k]
    for (int i = 0; i < 16; ++i) {
        const int idx = tid + i * 256;           // over 128n x 32 k-quads
        const int n = idx & 127, k4 = idx >> 7;
        const float w0 = w[(k4 * 4 + 0) * 384 + nt * 128 + n];
        const float w1 = w[(k4 * 4 + 1) * 384 + nt * 128 + n];
        const float w2 = w[(k4 * 4 + 2) * 384 + nt * 128 + n];
        const float w3 = w[(k4 * 4 + 3) * 384 + nt * 128 + n];
        *(ull*)(&wt[n * WR + k4 * 4]) = pk4(w0, w1, w2, w3);
    }
    __syncthreads();

    if (nt < 2) {
        // ---- Q/K: swapped operand order: C[m = w-col][n = x-row] ----
        unsigned short* outp = (nt == 0) ? qb : kb;
        const float sc = (nt == 0) ? 0.25503485952317864f : 1.0f;  // log2(e)/sqrt(32)
        f4 acc[8];
#pragma unroll
        for (int nf = 0; nf < 8; ++nf) {
            // n = nf*16 + quad*4 + r -> contiguous float4 of bias
            const float4 bv = *(const float4*)(bias + nt * 128 + nf * 16 + quad * 4);
            acc[nf] = (f4){bv.x, bv.y, bv.z, bv.w};
        }
#pragma unroll
        for (int ch = 0; ch < 4; ++ch) {
            const bh8 xf = *(const bh8*)(&xs[(wave * 16 + col) * XR + ch * 32 + quad * 8]);
#pragma unroll
            for (int nf = 0; nf < 8; ++nf) {
                const bh8 wf = *(const bh8*)(&wt[(nf * 16 + col) * WR + ch * 32 + quad * 8]);
                acc[nf] = __builtin_amdgcn_mfma_f32_16x16x32_bf16(wf, xf, acc[nf], 0, 0, 0);
            }
        }
        const int t = t0 + wave * 16 + col;        // this lane's seq row
#pragma unroll
        for (int nf = 0; nf < 8; ++nf) {
            const int h = nf >> 1;                 // n>>5
            const int dlo = (nf & 1) * 16 + quad * 4;
            const ull pv = (ull)cvt_pk_bf16(acc[nf][0] * sc, acc[nf][1] * sc)
                         | ((ull)cvt_pk_bf16(acc[nf][2] * sc, acc[nf][3] * sc) << 32);
            *(ull*)(outp + ((size_t)(b * NH + h) * T_SEQ + t) * HD + dlo) = pv;
        }
    } else {
        // ---- V: original orientation; C/D -> vt[n][m] LDS, then coalesced
        //      transposed writeout to [bh][d][t] ----
        f4 acc[8];
#pragma unroll
        for (int nf = 0; nf < 8; ++nf) {
            const float bv = bias[nt * 128 + nf * 16 + col];
            acc[nf] = (f4){bv, bv, bv, bv};
        }
#pragma unroll
        for (int ch = 0; ch < 4; ++ch) {
            const bh8 xf = *(const bh8*)(&xs[(wave * 16 + col) * XR + ch * 32 + quad * 8]);
#pragma unroll
            for (int nf = 0; nf < 8; ++nf) {
                const bh8 wf = *(const bh8*)(&wt[(nf * 16 + col) * WR + ch * 32 + quad * 8]);
                acc[nf] = __builtin_amdgcn_mfma_f32_16x16x32_bf16(xf, wf, acc[nf], 0, 0, 0);
            }
        }
        const int mrow = wave * 16 + quad * 4;     // rows mrow..mrow+3
#pragma unroll
        for (int nf = 0; nf < 8; ++nf) {
            const int n = nf * 16 + col;
            // rows are consecutive in vt[n][m] -> one b64 packed write
            *(ull*)(&vt[n * VR + mrow]) = pk4(acc[nf][0], acc[nf][1], acc[nf][2], acc[nf][3]);
        }
        __syncthreads();
        for (int i = 0; i < 16; ++i) {
            const int idx = tid + i * 256;       // over 128n x 32 uint-cols
            const int c = idx >> 5, dw = idx & 31;
            const int h2 = c >> 5, d2 = c & 31;
            const unsigned v0 = *(const unsigned*)(&vt[c * VR + dw * 2]);
            *(unsigned*)(vtb + ((size_t)(b * NH + h2) * HD + d2) * T_SEQ + t0 + dw * 2) = v0;
        }
    }
}

// ---------------------------------------------------------------------------
// Kernel 2: MFMA flash attention, no-max softmax, double-buffered staging.
// Swapped QK^T: z = mfma(kfrag, qfrag) -> lane holds S[key=16f+4*quad+r][q=col],
// so P packs with v_cvt_pk_bf16_f32 along keys and stores as b64 into [q][k].
// Grid 1024: one q-tile (64 queries) per block, 4 waves.
// CU-balanced qt map: co-resident blocks (same bid&255, c=bid>>8) get
// qt = {31-g, 16+g, 15-g, g}[c] -> sum(qt+1) = 66 for every CU.
// ---------------------------------------------------------------------------
__global__ __launch_bounds__(256, 4) void attn(const unsigned short* __restrict__ qb,
                                               const unsigned short* __restrict__ kb,
                                               const unsigned short* __restrict__ vtb,
                                               unsigned short* __restrict__ y) {
    constexpr int KROW = 40;
    constexpr int VROW = 72;
    constexpr int PROW = 72;
    __shared__ __align__(16) unsigned short Ks[2][64 * KROW];
    __shared__ __align__(16) unsigned short Vt[2][32 * VROW];
    __shared__ __align__(16) unsigned short Pb[4][16 * PROW];

    const int bid = blockIdx.x;
    const int bh = bid & 31;
    const int g = (bid >> 5) & 7;
    const int c = bid >> 8;           // 0..3: which co-residency round
    const int qt = (c == 0) ? (31 - g) : (c == 1) ? (16 + g) : (c == 2) ? (15 - g) : g;
    const int tid = threadIdx.x;
    const int wave = tid >> 6;
    const int lane = tid & 63;
    const int col = lane & 15;
    const int quad = lane >> 4;

    const unsigned short* kbase = kb + (size_t)bh * T_SEQ * HD;
    const unsigned short* vbase = vtb + (size_t)bh * HD * T_SEQ;
    const int ks_t = tid >> 2, ks_q = tid & 3;
    const int vs_d = tid >> 3, vs_s = tid & 7;

    const int q0 = qt * 64;
    const int ntiles = qt + 1;

    // Per-wave 16 queries: q = q0 + wave*16 + col (B-frag n-index)
    const bh8 qfrag = *(const bh8*)(qb + ((size_t)bh * T_SEQ + q0 + wave * 16 + col) * HD + quad * 8);
    f4 yacc0 = {0.f, 0.f, 0.f, 0.f}, yacc1 = {0.f, 0.f, 0.f, 0.f};
    float rs = 0.f;   // running denom for query = col (own 16 keys/iter)

    uint4 kreg = *(const uint4*)(kbase + (size_t)ks_t * HD + ks_q * 8);
    uint4 vreg = *(const uint4*)(vbase + (size_t)vs_d * T_SEQ + vs_s * 8);

    for (int kt = 0; kt < ntiles; ++kt) {
        const int buf = kt & 1;
        *(uint4*)(&Ks[buf][ks_t * KROW + ks_q * 8]) = kreg;
        *(uint4*)(&Vt[buf][vs_d * VROW + vs_s * 8]) = vreg;
        if (kt + 1 < ntiles) {
            kreg = *(const uint4*)(kbase + (size_t)((kt + 1) * 64 + ks_t) * HD + ks_q * 8);
            vreg = *(const uint4*)(vbase + (size_t)vs_d * T_SEQ + (kt + 1) * 64 + vs_s * 8);
        }
        __syncthreads();

        const bool diag = (kt == qt);
        f4 z[4];
#pragma unroll
        for (int f = 0; f < 4; ++f) {
            if (diag && f > wave) {
                z[f] = (f4){-1e30f, -1e30f, -1e30f, -1e30f};
            } else {
                // A = K (m = key), B = Q (n = query): same fragment loads, swapped args.
                const bh8 kfrag = *(const bh8*)(&Ks[buf][(f * 16 + col) * KROW + quad * 8]);
                f4 zz = {0.f, 0.f, 0.f, 0.f};
                zz = __builtin_amdgcn_mfma_f32_16x16x32_bf16(kfrag, qfrag, zz, 0, 0, 0);
                if (diag && f == wave) {
                    // mask key > query: (f*16 + quad*4 + r) > (wave*16 + col)
#pragma unroll
                    for (int r = 0; r < 4; ++r)
                        if (quad * 4 + r > col) zz[r] = -1e30f;
                }
                z[f] = zz;
            }
        }
        // exp2 + packed P store: element (q=col, k=f*16+quad*4+r) -> Pb[q][k]
#pragma unroll
        for (int f = 0; f < 4; ++f) {
            const float p0 = __builtin_amdgcn_exp2f(z[f][0]);
            const float p1 = __builtin_amdgcn_exp2f(z[f][1]);
            const float p2 = __builtin_amdgcn_exp2f(z[f][2]);
            const float p3 = __builtin_amdgcn_exp2f(z[f][3]);
            rs += (p0 + p1) + (p2 + p3);
            const unsigned d01 = cvt_pk_bf16(p0, p1);
            const unsigned d23 = cvt_pk_bf16(p2, p3);
            // col*PROW*2 bytes = col*144: 16B-aligned; + (f*16+quad*4)*2: 8B-aligned
            *(ull*)(&Pb[wave][col * PROW + f * 16 + quad * 4]) = (ull)d01 | ((ull)d23 << 32);
        }
#pragma unroll
        for (int kk = 0; kk < 2; ++kk) {
            const bh8 pf = *(const bh8*)(&Pb[wave][col * PROW + kk * 32 + quad * 8]);
            const bh8 v0 = *(const bh8*)(&Vt[buf][col * VROW + kk * 32 + quad * 8]);
            yacc0 = __builtin_amdgcn_mfma_f32_16x16x32_bf16(pf, v0, yacc0, 0, 0, 0);
            const bh8 v1 = *(const bh8*)(&Vt[buf][(16 + col) * VROW + kk * 32 + quad * 8]);
            yacc1 = __builtin_amdgcn_mfma_f32_16x16x32_bf16(pf, v1, yacc1, 0, 0, 0);
        }
    }

    // denom: rs holds sum over this lane's 16 keys/iter for query=col;
    // keys are spread across quads -> reduce across quads only.
    rs += __shfl_xor(rs, 16);
    rs += __shfl_xor(rs, 32);
    const float inv = 1.0f / rs;      // inverse denom for query = col

    const int bb = bh >> 2, hh = bh & 3;
    unsigned short* yp = y + ((size_t)bb * T_SEQ + q0 + wave * 16) * C_EMBD + hh * HD;
#pragma unroll
    for (int r = 0; r < 4; ++r) {
        // yacc row = query quad*4+r; fetch inv from lane with col == quad*4+r (same quad)
        const float invr = __shfl(inv, (lane & 48) | (quad * 4 + r));
        yp[(quad * 4 + r) * C_EMBD + col] = f2bf(yacc0[r] * invr);
        yp[(quad * 4 + r) * C_EMBD + 16 + col] = f2bf(yacc1[r] * invr);
    }
}

// ---------------------------------------------------------------------------
// Kernel 3: out = y @ w_proj + b_proj via MFMA. Grid 256 (64 rows each).
// Swapped operand order: C[m = w-col][n = y-row] -> acc[nf] is a float4 of
// 4 consecutive out cols -> 8 float4 stores/thread (was 32 dword stores).
// ---------------------------------------------------------------------------
__global__ __launch_bounds__(256) void out_mfma(const unsigned short* __restrict__ y,
                                                const float* __restrict__ w,
                                                const float* __restrict__ bias,
                                                float* __restrict__ out) {
    constexpr int YR = 136;
    constexpr int WR = 136;
    __shared__ __align__(16) unsigned short ys[64 * YR];
    __shared__ __align__(16) unsigned short wt[128 * WR];

    const int mt = blockIdx.x;
    const int row0 = mt * 64;
    const int tid = threadIdx.x;
    const int wave = tid >> 6;
    const int lane = tid & 63;
    const int col = lane & 15;
    const int quad = lane >> 4;

    // stage y tile 64x128 bf16 (direct copy)
    for (int i = 0; i < 4; ++i) {
        const int idx = tid + i * 256;           // over 1024 uint4
        const int row = idx >> 4, q8 = idx & 15;
        const uint4 v = *(const uint4*)(y + (size_t)(row0 + row) * C_EMBD + q8 * 8);
        *(uint4*)(&ys[row * YR + q8 * 8]) = v;
    }
    // stage w_proj [128k][128n] -> transposed bf16 wt[n][k]
    for (int i = 0; i < 16; ++i) {
        const int idx = tid + i * 256;
        const int n = idx & 127, k4 = idx >> 7;
        const float w0 = w[(k4 * 4 + 0) * C_EMBD + n];
        const float w1 = w[(k4 * 4 + 1) * C_EMBD + n];
        const float w2 = w[(k4 * 4 + 2) * C_EMBD + n];
        const float w3 = w[(k4 * 4 + 3) * C_EMBD + n];
        *(ull*)(&wt[n * WR + k4 * 4]) = pk4(w0, w1, w2, w3);
    }
    __syncthreads();

    f4 acc[8];
#pragma unroll
    for (int nf = 0; nf < 8; ++nf) {
        // n = nf*16 + quad*4 + r -> contiguous float4 of bias
        const float4 bv = *(const float4*)(bias + nf * 16 + quad * 4);
        acc[nf] = (f4){bv.x, bv.y, bv.z, bv.w};
    }
#pragma unroll
    for (int ch = 0; ch < 4; ++ch) {
        const bh8 yf = *(const bh8*)(&ys[(wave * 16 + col) * YR + ch * 32 + quad * 8]);
#pragma unroll
        for (int nf = 0; nf < 8; ++nf) {
            const bh8 wf = *(const bh8*)(&wt[(nf * 16 + col) * WR + ch * 32 + quad * 8]);
            acc[nf] = __builtin_amdgcn_mfma_f32_16x16x32_bf16(wf, yf, acc[nf], 0, 0, 0);
        }
    }

    const int t = row0 + wave * 16 + col;        // this lane's output row
#pragma unroll
    for (int nf = 0; nf < 8; ++nf)
        *(f4*)(out + (size_t)t * C_EMBD + nf * 16 + quad * 4) = acc[nf];
}

extern "C" void kernel_launch(void* const* d_in, const int* in_sizes, int n_in,
                              void* d_out, int out_size, void* d_ws, size_t ws_size,
                              hipStream_t stream) {
    const float* x      = (const float*)d_in[0];
    const float* w_qkv  = (const float*)d_in[1];
    const float* b_qkv  = (const float*)d_in[2];
    const float* w_proj = (const float*)d_in[3];
    const float* b_proj = (const float*)d_in[4];
    float* out = (float*)d_out;

    unsigned short* qb  = (unsigned short*)d_ws;                   // 4 MB
    unsigned short* kb  = qb + (size_t)BHT * T_SEQ * HD;           // 4 MB
    unsigned short* vtb = kb + (size_t)BHT * T_SEQ * HD;           // 4 MB
    unsigned short* yb  = vtb + (size_t)BHT * T_SEQ * HD;          // 4 MB (bf16 y)

    qkv_mfma<<<dim3(3, 256), 256, 0, stream>>>(x, w_qkv, b_qkv, qb, kb, vtb);
    attn<<<1024, 256, 0, stream>>>(qb, kb, vtb, yb);
    out_mfma<<<256, 256, 0, stream>>>(yb, w_proj, b_proj, out);
}

// Round 8
// 101.753 us; speedup vs baseline: 1.1196x; 1.0149x over previous
//
#include <hip/hip_runtime.h>
#include <hip/hip_bf16.h>
#include <stdint.h>

// CausalSelfAttention: B=8, T=2048, C=128, H=4, D=32. fp32 in / fp32 out.
// All three stages MFMA (bf16 inputs, fp32 accum):
//   qkv_mfma: qkv = x @ w_qkv + b. Q/K use SWAPPED mfma (rows = w-cols) so the
//             4 acc regs are consecutive d -> cvt_pk packed b64 stores (8/thread).
//             V keeps old orientation -> vt LDS transpose -> [bh][d][t].
//             (vt is a SEPARATE buffer: aliasing vt onto wt failed R6/R7.)
//   attn:     flash attention, no-max softmax, swapped QK^T (mfma(K,Q)),
//             cvt_pk packed P -> ds_write_b64 [q][k]. 1024 blocks, CU-balanced
//             qt map {31-g, 16+g, 15-g, g} -> 66 iters/CU.
//   out_mfma: out = y @ w_proj + b, SWAPPED mfma -> float4 stores (8/thread).
// ws: qb 4MB | kb 4MB | vtb 4MB | yb bf16 4MB = 16MB

#define T_SEQ 2048
#define C_EMBD 128
#define NH 4
#define HD 32
#define BATCH 8
#define BHT (BATCH * NH)

typedef float f4  __attribute__((ext_vector_type(4)));
typedef short bh8 __attribute__((ext_vector_type(8)));
typedef unsigned long long ull;

__device__ __forceinline__ unsigned short f2bf(float f) {
    union { float f; unsigned u; } v; v.f = f;
    return (unsigned short)((v.u + 0x7fffu + ((v.u >> 16) & 1u)) >> 16);
}
// v_cvt_pk_bf16_f32: lo16 = bf16(a), hi16 = bf16(b), RNE (== f2bf). No builtin.
__device__ __forceinline__ unsigned cvt_pk_bf16(float a, float b) {
    unsigned r;
    asm("v_cvt_pk_bf16_f32 %0, %1, %2" : "=v"(r) : "v"(a), "v"(b));
    return r;
}
__device__ __forceinline__ ull pk4(float a, float b, float c, float d) {
    return (ull)cvt_pk_bf16(a, b) | ((ull)cvt_pk_bf16(c, d) << 32);
}

// ---------------------------------------------------------------------------
// Kernel 1: qkv = x @ w_qkv + b_qkv via MFMA. Grid (nt=3, mt=256).
// Block: 256 thr = 4 waves; 64 rows x 128 cols per block, K=128.
// A[m=lane&15][k=quad*8+j], B[n=lane&15][k=quad*8+j], C/D[row=quad*4+r][col].
// Q/K: mfma(wf, xf) -> C rows = w-cols: regs are 4 consecutive d -> b64 stores.
// V:   mfma(xf, wf) -> C rows = t: vt LDS transpose -> coalesced [d][t] out.
// ---------------------------------------------------------------------------
__global__ __launch_bounds__(256) void qkv_mfma(const float* __restrict__ x,
                                                const float* __restrict__ w,
                                                const float* __restrict__ bias,
                                                unsigned short* __restrict__ qb,
                                                unsigned short* __restrict__ kb,
                                                unsigned short* __restrict__ vtb) {
    constexpr int XR = 136;   // xs row stride (elems): 272B, 16B-aligned
    constexpr int WR = 136;   // wt row stride
    constexpr int VR = 72;    // vt row stride
    __shared__ __align__(16) unsigned short xs[64 * XR];
    __shared__ __align__(16) unsigned short wt[128 * WR];
    __shared__ __align__(16) unsigned short vt[128 * VR];

    const int nt = blockIdx.x;        // 0=Q 1=K 2=V (column tile of 128)
    const int mt = blockIdx.y;        // row tile of 64
    const int t0g = mt * 64;          // global row
    const int b = t0g >> 11;          // batch
    const int t0 = t0g & 2047;        // seq pos within batch
    const int tid = threadIdx.x;
    const int wave = tid >> 6;
    const int lane = tid & 63;
    const int col = lane & 15;
    const int quad = lane >> 4;

    // stage x tile 64x128 fp32 -> bf16 LDS
    for (int i = 0; i < 8; ++i) {
        const int idx = tid + i * 256;           // over 2048 float4
        const int row = idx >> 5, c4 = idx & 31;
        const float4 xv = *(const float4*)(x + (size_t)(t0g + row) * C_EMBD + c4 * 4);
        *(ull*)(&xs[row * XR + c4 * 4]) = pk4(xv.x, xv.y, xv.z, xv.w);
    }
    // stage w slice [128k][128n] -> transposed bf16 LDS wt[n][k]
    for (int i = 0; i < 16; ++i) {
        const int idx = tid + i * 256;           // over 128n x 32 k-quads
        const int n = idx & 127, k4 = idx >> 7;
        const float w0 = w[(k4 * 4 + 0) * 384 + nt * 128 + n];
        const float w1 = w[(k4 * 4 + 1) * 384 + nt * 128 + n];
        const float w2 = w[(k4 * 4 + 2) * 384 + nt * 128 + n];
        const float w3 = w[(k4 * 4 + 3) * 384 + nt * 128 + n];
        *(ull*)(&wt[n * WR + k4 * 4]) = pk4(w0, w1, w2, w3);
    }
    __syncthreads();

    if (nt < 2) {
        // ---- Q/K: swapped operand order: C[m = w-col][n = x-row] ----
        unsigned short* outp = (nt == 0) ? qb : kb;
        const float sc = (nt == 0) ? 0.25503485952317864f : 1.0f;  // log2(e)/sqrt(32)
        f4 acc[8];
#pragma unroll
        for (int nf = 0; nf < 8; ++nf) {
            // n = nf*16 + quad*4 + r -> contiguous float4 of bias
            const float4 bv = *(const float4*)(bias + nt * 128 + nf * 16 + quad * 4);
            acc[nf] = (f4){bv.x, bv.y, bv.z, bv.w};
        }
#pragma unroll
        for (int ch = 0; ch < 4; ++ch) {
            const bh8 xf = *(const bh8*)(&xs[(wave * 16 + col) * XR + ch * 32 + quad * 8]);
#pragma unroll
            for (int nf = 0; nf < 8; ++nf) {
                const bh8 wf = *(const bh8*)(&wt[(nf * 16 + col) * WR + ch * 32 + quad * 8]);
                acc[nf] = __builtin_amdgcn_mfma_f32_16x16x32_bf16(wf, xf, acc[nf], 0, 0, 0);
            }
        }
        const int t = t0 + wave * 16 + col;        // this lane's seq row
#pragma unroll
        for (int nf = 0; nf < 8; ++nf) {
            const int h = nf >> 1;                 // n>>5
            const int dlo = (nf & 1) * 16 + quad * 4;
            const ull pv = (ull)cvt_pk_bf16(acc[nf][0] * sc, acc[nf][1] * sc)
                         | ((ull)cvt_pk_bf16(acc[nf][2] * sc, acc[nf][3] * sc) << 32);
            *(ull*)(outp + ((size_t)(b * NH + h) * T_SEQ + t) * HD + dlo) = pv;
        }
    } else {
        // ---- V: original orientation; C/D -> vt[n][m] LDS, then coalesced
        //      transposed writeout to [bh][d][t] ----
        f4 acc[8];
#pragma unroll
        for (int nf = 0; nf < 8; ++nf) {
            const float bv = bias[nt * 128 + nf * 16 + col];
            acc[nf] = (f4){bv, bv, bv, bv};
        }
#pragma unroll
        for (int ch = 0; ch < 4; ++ch) {
            const bh8 xf = *(const bh8*)(&xs[(wave * 16 + col) * XR + ch * 32 + quad * 8]);
#pragma unroll
            for (int nf = 0; nf < 8; ++nf) {
                const bh8 wf = *(const bh8*)(&wt[(nf * 16 + col) * WR + ch * 32 + quad * 8]);
                acc[nf] = __builtin_amdgcn_mfma_f32_16x16x32_bf16(xf, wf, acc[nf], 0, 0, 0);
            }
        }
        const int mrow = wave * 16 + quad * 4;     // rows mrow..mrow+3
#pragma unroll
        for (int nf = 0; nf < 8; ++nf) {
            const int n = nf * 16 + col;
            // rows are consecutive in vt[n][m] -> one b64 packed write
            *(ull*)(&vt[n * VR + mrow]) = pk4(acc[nf][0], acc[nf][1], acc[nf][2], acc[nf][3]);
        }
        __syncthreads();
        for (int i = 0; i < 16; ++i) {
            const int idx = tid + i * 256;       // over 128n x 32 uint-cols
            const int c = idx >> 5, dw = idx & 31;
            const int h2 = c >> 5, d2 = c & 31;
            const unsigned v0 = *(const unsigned*)(&vt[c * VR + dw * 2]);
            *(unsigned*)(vtb + ((size_t)(b * NH + h2) * HD + d2) * T_SEQ + t0 + dw * 2) = v0;
        }
    }
}

// ---------------------------------------------------------------------------
// Kernel 2: MFMA flash attention, no-max softmax, double-buffered staging.
// Swapped QK^T: z = mfma(kfrag, qfrag) -> lane holds S[key=16f+4*quad+r][q=col],
// so P packs with v_cvt_pk_bf16_f32 along keys and stores as b64 into [q][k].
// Grid 1024: one q-tile (64 queries) per block, 4 waves.
// CU-balanced qt map: co-resident blocks (same bid&255, c=bid>>8) get
// qt = {31-g, 16+g, 15-g, g}[c] -> sum(qt+1) = 66 for every CU.
// ---------------------------------------------------------------------------
__global__ __launch_bounds__(256, 4) void attn(const unsigned short* __restrict__ qb,
                                               const unsigned short* __restrict__ kb,
                                               const unsigned short* __restrict__ vtb,
                                               unsigned short* __restrict__ y) {
    constexpr int KROW = 40;
    constexpr int VROW = 72;
    constexpr int PROW = 72;
    __shared__ __align__(16) unsigned short Ks[2][64 * KROW];
    __shared__ __align__(16) unsigned short Vt[2][32 * VROW];
    __shared__ __align__(16) unsigned short Pb[4][16 * PROW];

    const int bid = blockIdx.x;
    const int bh = bid & 31;
    const int g = (bid >> 5) & 7;
    const int c = bid >> 8;           // 0..3: which co-residency round
    const int qt = (c == 0) ? (31 - g) : (c == 1) ? (16 + g) : (c == 2) ? (15 - g) : g;
    const int tid = threadIdx.x;
    const int wave = tid >> 6;
    const int lane = tid & 63;
    const int col = lane & 15;
    const int quad = lane >> 4;

    const unsigned short* kbase = kb + (size_t)bh * T_SEQ * HD;
    const unsigned short* vbase = vtb + (size_t)bh * HD * T_SEQ;
    const int ks_t = tid >> 2, ks_q = tid & 3;
    const int vs_d = tid >> 3, vs_s = tid & 7;

    const int q0 = qt * 64;
    const int ntiles = qt + 1;

    // Per-wave 16 queries: q = q0 + wave*16 + col (B-frag n-index)
    const bh8 qfrag = *(const bh8*)(qb + ((size_t)bh * T_SEQ + q0 + wave * 16 + col) * HD + quad * 8);
    f4 yacc0 = {0.f, 0.f, 0.f, 0.f}, yacc1 = {0.f, 0.f, 0.f, 0.f};
    float rs = 0.f;   // running denom for query = col (own 16 keys/iter)

    uint4 kreg = *(const uint4*)(kbase + (size_t)ks_t * HD + ks_q * 8);
    uint4 vreg = *(const uint4*)(vbase + (size_t)vs_d * T_SEQ + vs_s * 8);

    for (int kt = 0; kt < ntiles; ++kt) {
        const int buf = kt & 1;
        *(uint4*)(&Ks[buf][ks_t * KROW + ks_q * 8]) = kreg;
        *(uint4*)(&Vt[buf][vs_d * VROW + vs_s * 8]) = vreg;
        if (kt + 1 < ntiles) {
            kreg = *(const uint4*)(kbase + (size_t)((kt + 1) * 64 + ks_t) * HD + ks_q * 8);
            vreg = *(const uint4*)(vbase + (size_t)vs_d * T_SEQ + (kt + 1) * 64 + vs_s * 8);
        }
        __syncthreads();

        const bool diag = (kt == qt);
        f4 z[4];
#pragma unroll
        for (int f = 0; f < 4; ++f) {
            if (diag && f > wave) {
                z[f] = (f4){-1e30f, -1e30f, -1e30f, -1e30f};
            } else {
                // A = K (m = key), B = Q (n = query): same fragment loads, swapped args.
                const bh8 kfrag = *(const bh8*)(&Ks[buf][(f * 16 + col) * KROW + quad * 8]);
                f4 zz = {0.f, 0.f, 0.f, 0.f};
                zz = __builtin_amdgcn_mfma_f32_16x16x32_bf16(kfrag, qfrag, zz, 0, 0, 0);
                if (diag && f == wave) {
                    // mask key > query: (f*16 + quad*4 + r) > (wave*16 + col)
#pragma unroll
                    for (int r = 0; r < 4; ++r)
                        if (quad * 4 + r > col) zz[r] = -1e30f;
                }
                z[f] = zz;
            }
        }
        // exp2 + packed P store: element (q=col, k=f*16+quad*4+r) -> Pb[q][k]
#pragma unroll
        for (int f = 0; f < 4; ++f) {
            const float p0 = __builtin_amdgcn_exp2f(z[f][0]);
            const float p1 = __builtin_amdgcn_exp2f(z[f][1]);
            const float p2 = __builtin_amdgcn_exp2f(z[f][2]);
            const float p3 = __builtin_amdgcn_exp2f(z[f][3]);
            rs += (p0 + p1) + (p2 + p3);
            const unsigned d01 = cvt_pk_bf16(p0, p1);
            const unsigned d23 = cvt_pk_bf16(p2, p3);
            // col*PROW*2 bytes = col*144: 16B-aligned; + (f*16+quad*4)*2: 8B-aligned
            *(ull*)(&Pb[wave][col * PROW + f * 16 + quad * 4]) = (ull)d01 | ((ull)d23 << 32);
        }
#pragma unroll
        for (int kk = 0; kk < 2; ++kk) {
            const bh8 pf = *(const bh8*)(&Pb[wave][col * PROW + kk * 32 + quad * 8]);
            const bh8 v0 = *(const bh8*)(&Vt[buf][col * VROW + kk * 32 + quad * 8]);
            yacc0 = __builtin_amdgcn_mfma_f32_16x16x32_bf16(pf, v0, yacc0, 0, 0, 0);
            const bh8 v1 = *(const bh8*)(&Vt[buf][(16 + col) * VROW + kk * 32 + quad * 8]);
            yacc1 = __builtin_amdgcn_mfma_f32_16x16x32_bf16(pf, v1, yacc1, 0, 0, 0);
        }
    }

    // denom: rs holds sum over this lane's 16 keys/iter for query=col;
    // keys are spread across quads -> reduce across quads only.
    rs += __shfl_xor(rs, 16);
    rs += __shfl_xor(rs, 32);
    const float inv = 1.0f / rs;      // inverse denom for query = col

    const int bb = bh >> 2, hh = bh & 3;
    unsigned short* yp = y + ((size_t)bb * T_SEQ + q0 + wave * 16) * C_EMBD + hh * HD;
#pragma unroll
    for (int r = 0; r < 4; ++r) {
        // yacc row = query quad*4+r; fetch inv from lane with col == quad*4+r (same quad)
        const float invr = __shfl(inv, (lane & 48) | (quad * 4 + r));
        yp[(quad * 4 + r) * C_EMBD + col] = f2bf(yacc0[r] * invr);
        yp[(quad * 4 + r) * C_EMBD + 16 + col] = f2bf(yacc1[r] * invr);
    }
}

// ---------------------------------------------------------------------------
// Kernel 3: out = y @ w_proj + b_proj via MFMA. Grid 256 (64 rows each).
// Swapped operand order: C[m = w-col][n = y-row] -> acc[nf] is a float4 of
// 4 consecutive out cols -> 8 float4 stores/thread (was 32 dword stores).
// ---------------------------------------------------------------------------
__global__ __launch_bounds__(256) void out_mfma(const unsigned short* __restrict__ y,
                                                const float* __restrict__ w,
                                                const float* __restrict__ bias,
                                                float* __restrict__ out) {
    constexpr int YR = 136;
    constexpr int WR = 136;
    __shared__ __align__(16) unsigned short ys[64 * YR];
    __shared__ __align__(16) unsigned short wt[128 * WR];

    const int mt = blockIdx.x;
    const int row0 = mt * 64;
    const int tid = threadIdx.x;
    const int wave = tid >> 6;
    const int lane = tid & 63;
    const int col = lane & 15;
    const int quad = lane >> 4;

    // stage y tile 64x128 bf16 (direct copy)
    for (int i = 0; i < 4; ++i) {
        const int idx = tid + i * 256;           // over 1024 uint4
        const int row = idx >> 4, q8 = idx & 15;
        const uint4 v = *(const uint4*)(y + (size_t)(row0 + row) * C_EMBD + q8 * 8);
        *(uint4*)(&ys[row * YR + q8 * 8]) = v;
    }
    // stage w_proj [128k][128n] -> transposed bf16 wt[n][k]
    for (int i = 0; i < 16; ++i) {
        const int idx = tid + i * 256;
        const int n = idx & 127, k4 = idx >> 7;
        const float w0 = w[(k4 * 4 + 0) * C_EMBD + n];
        const float w1 = w[(k4 * 4 + 1) * C_EMBD + n];
        const float w2 = w[(k4 * 4 + 2) * C_EMBD + n];
        const float w3 = w[(k4 * 4 + 3) * C_EMBD + n];
        *(ull*)(&wt[n * WR + k4 * 4]) = pk4(w0, w1, w2, w3);
    }
    __syncthreads();

    f4 acc[8];
#pragma unroll
    for (int nf = 0; nf < 8; ++nf) {
        // n = nf*16 + quad*4 + r -> contiguous float4 of bias
        const float4 bv = *(const float4*)(bias + nf * 16 + quad * 4);
        acc[nf] = (f4){bv.x, bv.y, bv.z, bv.w};
    }
#pragma unroll
    for (int ch = 0; ch < 4; ++ch) {
        const bh8 yf = *(const bh8*)(&ys[(wave * 16 + col) * YR + ch * 32 + quad * 8]);
#pragma unroll
        for (int nf = 0; nf < 8; ++nf) {
            const bh8 wf = *(const bh8*)(&wt[(nf * 16 + col) * WR + ch * 32 + quad * 8]);
            acc[nf] = __builtin_amdgcn_mfma_f32_16x16x32_bf16(wf, yf, acc[nf], 0, 0, 0);
        }
    }

    const int t = row0 + wave * 16 + col;        // this lane's output row
#pragma unroll
    for (int nf = 0; nf < 8; ++nf)
        *(f4*)(out + (size_t)t * C_EMBD + nf * 16 + quad * 4) = acc[nf];
}

extern "C" void kernel_launch(void* const* d_in, const int* in_sizes, int n_in,
                              void* d_out, int out_size, void* d_ws, size_t ws_size,
                              hipStream_t stream) {
    const float* x      = (const float*)d_in[0];
    const float* w_qkv  = (const float*)d_in[1];
    const float* b_qkv  = (const float*)d_in[2];
    const float* w_proj = (const float*)d_in[3];
    const float* b_proj = (const float*)d_in[4];
    float* out = (float*)d_out;

    unsigned short* qb  = (unsigned short*)d_ws;                   // 4 MB
    unsigned short* kb  = qb + (size_t)BHT * T_SEQ * HD;           // 4 MB
    unsigned short* vtb = kb + (size_t)BHT * T_SEQ * HD;           // 4 MB
    unsigned short* yb  = vtb + (size_t)BHT * T_SEQ * HD;          // 4 MB (bf16 y)

    qkv_mfma<<<dim3(3, 256), 256, 0, stream>>>(x, w_qkv, b_qkv, qb, kb, vtb);
    attn<<<1024, 256, 0, stream>>>(qb, kb, vtb, yb);
    out_mfma<<<256, 256, 0, stream>>>(yb, w_proj, b_proj, out);
}